// Round 3
// baseline (105.651 us; speedup 1.0000x reference)
//
#include <hip/hip_runtime.h>
#include <hip/hip_bf16.h>

#define Bsz 256
#define Tn 2048
#define QD 1024
#define AD 128
#define DCn 8
#define DKn 21
#define PLn 11
#define GN (DCn * DKn)   // 168

typedef _Float16 f16x8 __attribute__((ext_vector_type(8)));
typedef float f32x4 __attribute__((ext_vector_type(4)));
typedef unsigned int u32;

#define TWO_LOG2E 2.8853900817779268f   // 2*log2(e): folds tanh's 2x and exp->exp2

// RNE pack of two floats into a (f16,f16) dword — matches (_Float16) cast rounding.
__device__ __forceinline__ u32 pkh_rne(float a, float b) {
    union { _Float16 h[2]; u32 u; } p;
    p.h[0] = (_Float16)a; p.h[1] = (_Float16)b;
    return p.u;
}

// ---------------------------------------------------------------------------
// Single fused kernel. Per b (one 1024-thread block):
//   [stage]    al16 staged via float4 loads + packed b32 LDS writes
//   [g-phase1] h = tanh(W_w q + W_b)  (L2-BW floor ~4 us, all waves)
//   [window]   between barrier-1 and barrier-2, overlapped:
//                g-phase2: G = V_w h, 4-way split over 672 threads
//                          (8 independent float4 loads each + 2 width-4
//                          shfl_xor combine — was a 128-deep serial chain
//                          on 168 threads),
//                prior conv, Bf/vnq build (global loads fly under g2),
//                iter-0 Ac preload.
//   [main]     per wave, 4 iters x 2 tiles of 16 t, zero block barriers:
//              SWAPPED conv-MFMA -> in-register bpermute transpose ->
//              proj-MFMA swapped -> sigmoid via exp2/rcp -> quad reduce.
//              Next iter's Ac ds_reads prefetched before the n-loop.
//   [softmax]  s = pcb * exp(e_inner) on 32 lanes; block sum; normalize.
// ---------------------------------------------------------------------------
__global__ __launch_bounds__(1024, 4) void dca_kernel(
    const float* __restrict__ query, const float* __restrict__ align,
    const float* __restrict__ P, const float* __restrict__ W_w,
    const float* __restrict__ W_b, const float* __restrict__ V_w,
    const float* __restrict__ F_w, const float* __restrict__ U_w,
    const float* __restrict__ T_w, const float* __restrict__ T_b,
    const float* __restrict__ v_w, float* __restrict__ out)
{
    __shared__ __align__(16) _Float16 al16[Tn + 44];
    __shared__ float    pcb[Tn];
    __shared__ float    sden[Tn];
    __shared__ __align__(16) float h_lds[AD];
    __shared__ float    G_lds[GN];
    __shared__ float    red[16];
    __shared__ float    bc;

    const int b    = blockIdx.x;
    const int tid  = threadIdx.x;
    const int lane = tid & 63;
    const int wid  = tid >> 6;
    const int l15  = lane & 15;
    const int quad = lane >> 4;

    // ---- stage alignment row as f16 (pad=10 each side; index i ~ t=i-10) ----
    if (tid < 512) {
        float4 v = ((const float4*)(align + (size_t)b * Tn))[tid];
        u32* dst = (u32*)&al16[10 + tid * 4];   // byte off 20+8*tid: 4B aligned
        dst[0] = pkh_rne(v.x, v.y);
        dst[1] = pkh_rne(v.z, v.w);
    } else if (tid < 576) {
        int k = tid - 512;
        if (k < 10)       al16[k]      = (_Float16)0.f;   // left pad 0..9
        else if (k < 44)  al16[Tn + k] = (_Float16)0.f;   // right pad Tn+10..Tn+43
    }

    // ---- g-phase 1: h = tanh(W_w q + W_b); wave handles 8 a-rows ----
    {
        const float4* q4 = (const float4*)(query + (size_t)b * QD);
        float4 q0 = q4[lane];
        float4 q1 = q4[64 + lane];
        float4 q2 = q4[128 + lane];
        float4 q3 = q4[192 + lane];
        #pragma unroll 2
        for (int i = 0; i < 8; ++i) {
            int a = wid * 8 + i;
            const float4* w4 = (const float4*)(W_w + (size_t)a * QD);
            float4 x0 = w4[lane];
            float4 x1 = w4[64 + lane];
            float4 x2 = w4[128 + lane];
            float4 x3 = w4[192 + lane];
            float accA = 0.f, accB = 0.f;
            accA = fmaf(q0.x, x0.x, fmaf(q0.y, x0.y, fmaf(q0.z, x0.z, fmaf(q0.w, x0.w, accA))));
            accB = fmaf(q1.x, x1.x, fmaf(q1.y, x1.y, fmaf(q1.z, x1.z, fmaf(q1.w, x1.w, accB))));
            accA = fmaf(q2.x, x2.x, fmaf(q2.y, x2.y, fmaf(q2.z, x2.z, fmaf(q2.w, x2.w, accA))));
            accB = fmaf(q3.x, x3.x, fmaf(q3.y, x3.y, fmaf(q3.z, x3.z, fmaf(q3.w, x3.w, accB))));
            float acc = accA + accB;
            #pragma unroll
            for (int off = 32; off; off >>= 1) acc += __shfl_xor(acc, off);
            if (lane == 0) h_lds[a] = tanhf(acc + W_b[a]);
        }
    }
    __syncthreads();   // h_lds + al16 ready

    // ---- g-phase 2 (4-way split): G[r] = V_w[r] . h, r = tid>>2, seg = tid&3 ----
    if (tid < 4 * GN) {
        const int r = tid >> 2;
        const int s = tid & 3;
        const float4* v4 = (const float4*)(V_w + (size_t)r * AD + s * 32);
        const float4* h4 = (const float4*)(h_lds + s * 32);
        float g = 0.f;
        #pragma unroll
        for (int i = 0; i < 8; ++i) {
            float4 vv = v4[i];
            float4 hh = h4[i];
            g = fmaf(vv.x, hh.x, fmaf(vv.y, hh.y, fmaf(vv.z, hh.z, fmaf(vv.w, hh.w, g))));
        }
        g += __shfl_xor(g, 1);
        g += __shfl_xor(g, 2);
        if (s == 0) G_lds[r] = g;
    }

    // ---- prior, wave-local (same wave writes & reads its pcb range) ----
    const int t0w = wid * 128;
    #pragma unroll
    for (int tt = 0; tt < 2; ++tt) {
        int t = t0w + tt * 64 + lane;
        float pr = 0.f;
        #pragma unroll
        for (int k = 0; k < PLn; ++k) pr = fmaf((float)al16[t + k], P[k], pr);
        pcb[t] = fmaxf(pr, 1e-6f);
    }

    // ---- proj weight frags (MFMA *A* operand: A[m=a_loc=l15][k]) ----
    // Hoisted into the g2 window: U_w/T_w/v_w loads overlap g2's V_w loads.
    // k=0..7: U (f-channels), k=8..15: T (g-channels), k=16: bias channel.
    f16x8 Bf[8];
    #pragma unroll
    for (int n = 0; n < 8; ++n) {
        int a = n * 16 + l15;
        f16x8 bf = {};
        if (quad < 2) {
            const float* src = (quad == 0) ? (U_w + a * 8) : (T_w + a * 8);
            float4 lo = ((const float4*)src)[0];
            float4 hi = ((const float4*)src)[1];
            bf[0] = (_Float16)(TWO_LOG2E * lo.x); bf[1] = (_Float16)(TWO_LOG2E * lo.y);
            bf[2] = (_Float16)(TWO_LOG2E * lo.z); bf[3] = (_Float16)(TWO_LOG2E * lo.w);
            bf[4] = (_Float16)(TWO_LOG2E * hi.x); bf[5] = (_Float16)(TWO_LOG2E * hi.y);
            bf[6] = (_Float16)(TWO_LOG2E * hi.z); bf[7] = (_Float16)(TWO_LOG2E * hi.w);
        } else if (quad == 2) {
            bf[0] = (_Float16)(TWO_LOG2E * T_b[a]);   // k=16 bias channel
        }
        Bf[n] = bf;
    }

    // ---- in-lane v-weights: vnq[n][r] = -2*v_w[n*16 + quad*4 + r] ----
    f32x4 vnq[8];
    float vsum = 0.f;
    #pragma unroll
    for (int n = 0; n < 8; ++n) {
        f32x4 vq = *(const f32x4*)(v_w + n * 16 + quad * 4);
        vsum += vq[0] + vq[1] + vq[2] + vq[3];
        vq[0] *= -2.f; vq[1] *= -2.f; vq[2] *= -2.f; vq[3] *= -2.f;
        vnq[n] = vq;
    }
    vsum += __shfl_xor(vsum, 16);
    vsum += __shfl_xor(vsum, 32);   // full sum over 128 a's

    // ---- iter-0 conv al-frags preload (al16 ready since barrier-1) ----
    f16x8 Ac0, Ac1;
    #pragma unroll
    for (int j = 0; j < 8; ++j) {
        Ac0[j] = al16[t0w      + l15 + quad * 8 + j];
        Ac1[j] = al16[t0w + 16 + l15 + quad * 8 + j];
    }

    __syncthreads();   // G_lds ready

    // ---- conv weight frag (MFMA *A* operand): A[m=c=l15][k=tap=quad*8+j] ----
    f16x8 Bc = {};
    #pragma unroll
    for (int j = 0; j < 8; ++j) {
        int k = quad * 8 + j;
        float wv = 0.f;
        if (k < DKn) wv = (l15 < 8) ? F_w[l15 * DKn + k]
                                    : G_lds[(l15 - 8) * DKn + k];
        Bc[j] = (_Float16)wv;
    }

    // bpermute source addresses: target (quad,l15) pulls from lanes
    // (2*quad)*16+l15 (srcA: c=quad*8+0..3) and +16 (srcB: c=quad*8+4..7).
    // quad>=2 wraps to garbage lanes — harmless (Bf zero there), except the
    // bias word k=16 which is overwritten below.
    const int addrA = ((((lane & 48) << 1) | (lane & 15)) << 2);
    const int addrB = addrA + 64;

    // ---- wave-local main loop: 4 iterations of 2 tiles (32 t) ----
    float wsum = 0.f;

    #pragma unroll 1
    for (int m = 0; m < 8; m += 2) {
        const int ta  = t0w + m * 16;
        const int tb_ = ta + 16;

        f32x4 z = {};
        // swapped conv: D[m=c][n=t]; lane holds c=quad*4+r, t=ta+l15
        f32x4 X0 = __builtin_amdgcn_mfma_f32_16x16x32_f16(Bc, Ac0, z, 0, 0, 0);
        f32x4 X1 = __builtin_amdgcn_mfma_f32_16x16x32_f16(Bc, Ac1, z, 0, 0, 0);

        // prefetch next iteration's al-frags (hides ds_read latency under n-loop)
        if (m < 6) {
            #pragma unroll
            for (int j = 0; j < 8; ++j) {
                Ac0[j] = al16[ta  + 32 + l15 + quad * 8 + j];
                Ac1[j] = al16[tb_ + 32 + l15 + quad * 8 + j];
            }
        }

        // in-register transpose gather: proj B-frag B2[k=c=quad*8+j][n=t=l15]
        u32 lo0 = pkh_rne(X0[0], X0[1]), hi0 = pkh_rne(X0[2], X0[3]);
        u32 lo1 = pkh_rne(X1[0], X1[1]), hi1 = pkh_rne(X1[2], X1[3]);

        union { u32 w[4]; f16x8 v; } U0, U1;
        U0.w[0] = (u32)__builtin_amdgcn_ds_bpermute(addrA, (int)lo0);
        U0.w[1] = (u32)__builtin_amdgcn_ds_bpermute(addrA, (int)hi0);
        U0.w[2] = (u32)__builtin_amdgcn_ds_bpermute(addrB, (int)lo0);
        U0.w[3] = (u32)__builtin_amdgcn_ds_bpermute(addrB, (int)hi0);
        U1.w[0] = (u32)__builtin_amdgcn_ds_bpermute(addrA, (int)lo1);
        U1.w[1] = (u32)__builtin_amdgcn_ds_bpermute(addrA, (int)hi1);
        U1.w[2] = (u32)__builtin_amdgcn_ds_bpermute(addrB, (int)lo1);
        U1.w[3] = (u32)__builtin_amdgcn_ds_bpermute(addrB, (int)hi1);
        if (quad == 2) {                  // k=16 bias channel = 1.0 (k=17 -> 0)
            U0.w[0] = 0x3C00u;
            U1.w[0] = 0x3C00u;
        }

        float es0 = 0.f, es1 = 0.f;
        #pragma unroll
        for (int n = 0; n < 8; ++n) {
            f32x4 z2 = {};
            // swapped operands: D[m=a_loc][n=t]: row=a_loc=quad*4+r, col=t=l15
            f32x4 d0 = __builtin_amdgcn_mfma_f32_16x16x32_f16(Bf[n], U0.v, z2, 0, 0, 0);
            f32x4 d1 = __builtin_amdgcn_mfma_f32_16x16x32_f16(Bf[n], U1.v, z2, 0, 0, 0);
            #pragma unroll
            for (int r = 0; r < 4; ++r) {
                float qa = __builtin_amdgcn_exp2f(d0[r]);
                float qb = __builtin_amdgcn_exp2f(d1[r]);
                float ra = __builtin_amdgcn_rcpf(qa + 1.f);
                float rb = __builtin_amdgcn_rcpf(qb + 1.f);
                es0 = fmaf(vnq[n][r], ra, es0);
                es1 = fmaf(vnq[n][r], rb, es1);
            }
        }
        // full a-reduction: only across quads (t = l15 is the lane col)
        es0 += __shfl_xor(es0, 16);
        es0 += __shfl_xor(es0, 32);
        es1 += __shfl_xor(es1, 16);
        es1 += __shfl_xor(es1, 32);

        // epilogue on 32 lanes: tile A -> lanes 0-15, tile B -> lanes 16-31
        if (lane < 32) {
            int t    = ((lane < 16) ? ta : tb_) + l15;
            float e  = (lane < 16) ? es0 : es1;
            float sv = pcb[t] * __expf(e + vsum);
            sden[t] = sv;
            wsum += sv;
        }
    }

    // ---- block sum + normalize ----
    __syncthreads();
    #pragma unroll
    for (int off = 32; off; off >>= 1) wsum += __shfl_xor(wsum, off);
    if (lane == 0) red[wid] = wsum;
    __syncthreads();
    if (wid == 0) {
        float ss = (lane < 16) ? red[lane] : 0.f;
        #pragma unroll
        for (int off = 8; off; off >>= 1) ss += __shfl_xor(ss, off);
        if (lane == 0) bc = ss;
    }
    __syncthreads();
    const float inv = 1.f / bc;
    out[b * Tn + tid]        = sden[tid] * inv;
    out[b * Tn + tid + 1024] = sden[tid + 1024] * inv;
}

// ---------------------------------------------------------------------------
extern "C" void kernel_launch(void* const* d_in, const int* in_sizes, int n_in,
                              void* d_out, int out_size, void* d_ws, size_t ws_size,
                              hipStream_t stream) {
    const float* query = (const float*)d_in[0];
    const float* align = (const float*)d_in[1];
    const float* P     = (const float*)d_in[2];
    const float* W_w   = (const float*)d_in[3];
    const float* W_b   = (const float*)d_in[4];
    const float* V_w   = (const float*)d_in[5];
    const float* F_w   = (const float*)d_in[6];
    const float* U_w   = (const float*)d_in[7];
    const float* T_w   = (const float*)d_in[8];
    const float* T_b   = (const float*)d_in[9];
    const float* v_w   = (const float*)d_in[10];
    float* out = (float*)d_out;

    dca_kernel<<<Bsz, 1024, 0, stream>>>(query, align, P, W_w, W_b, V_w,
                                         F_w, U_w, T_w, T_b, v_w, out);
}

// Round 4
// 100.573 us; speedup vs baseline: 1.0505x; 1.0505x over previous
//
#include <hip/hip_runtime.h>
#include <hip/hip_bf16.h>

#define Bsz 256
#define Tn 2048
#define QD 1024
#define AD 128
#define DCn 8
#define DKn 21
#define PLn 11
#define GN (DCn * DKn)   // 168
#define MS 32            // M16 row stride in halfs (64 B rows, 16B-aligned frags)

typedef _Float16 f16x8 __attribute__((ext_vector_type(8)));
typedef float f32x4 __attribute__((ext_vector_type(4)));
typedef unsigned int u32;

#define TWO_LOG2E 2.8853900817779268f   // 2*log2(e): folds tanh's 2x and exp->exp2

// RNE pack of two floats into a (f16,f16) dword — matches (_Float16) cast rounding.
__device__ __forceinline__ u32 pkh_rne(float a, float b) {
    union { _Float16 h[2]; u32 u; } p;
    p.h[0] = (_Float16)a; p.h[1] = (_Float16)b;
    return p.u;
}

// ---------------------------------------------------------------------------
// Algebraic fusion: z[t][a] = sum_k win[t][k]*M[a][k] + b[a], with
//   M = U_w . F  +  T_w . G_b   (128 x 21, per batch; both convs and the
// projection are linear before tanh, so they collapse into ONE im2col GEMM).
// This removes the per-iteration conv-MFMA -> pack -> bpermute -> proj-MFMA
// dependency chain entirely: the main loop is 16 independent MFMAs + sigmoid.
//
// Phases per b (one 1024-thread block):
//   P0: stage al16 (f16, pad 10/34); g1: h = tanh(W_w q + W_b)   [barrier]
//   P1: g2: G = V_w h (4-way split); prior pcb; vnq/vsum; M A-frag (U|T rows)
//       and F-part of M B-frag (no G dependency)                 [barrier]
//   P2: G-part of B-frag; one MFMA per wave -> M16[128][32] in LDS
//       (k=21 col = bias*2log2e, k in 22..31 = 0)                [barrier]
//   P3: Mf frags (8 x ds_read_b128); main loop 4 iters x 2 tiles:
//       d = mfma(Mf[n], Ac) -> sigmoid exp2/rcp -> quad reduce -> sden
//   P4: block sum; normalize; write out.
// ---------------------------------------------------------------------------
__global__ __launch_bounds__(1024, 4) void dca_kernel(
    const float* __restrict__ query, const float* __restrict__ align,
    const float* __restrict__ P, const float* __restrict__ W_w,
    const float* __restrict__ W_b, const float* __restrict__ V_w,
    const float* __restrict__ F_w, const float* __restrict__ U_w,
    const float* __restrict__ T_w, const float* __restrict__ T_b,
    const float* __restrict__ v_w, float* __restrict__ out)
{
    __shared__ __align__(16) _Float16 al16[Tn + 44];
    __shared__ float    pcb[Tn];
    __shared__ float    sden[Tn];
    __shared__ __align__(16) float h_lds[AD];
    __shared__ float    G_lds[GN];
    __shared__ __align__(16) _Float16 M16[AD * MS];   // 8 KB fused weights
    __shared__ float    red[16];
    __shared__ float    bc;

    const int b    = blockIdx.x;
    const int tid  = threadIdx.x;
    const int lane = tid & 63;
    const int wid  = tid >> 6;
    const int l15  = lane & 15;
    const int quad = lane >> 4;

    // ---- P0: stage alignment row as f16 (pad=10 each side; i ~ t=i-10) ----
    if (tid < 512) {
        float4 v = ((const float4*)(align + (size_t)b * Tn))[tid];
        u32* dst = (u32*)&al16[10 + tid * 4];
        dst[0] = pkh_rne(v.x, v.y);
        dst[1] = pkh_rne(v.z, v.w);
    } else if (tid < 576) {
        int k = tid - 512;
        if (k < 10)       al16[k]      = (_Float16)0.f;
        else if (k < 44)  al16[Tn + k] = (_Float16)0.f;
    }

    // ---- P0: g1: h = tanh(W_w q + W_b); wave handles 8 a-rows ----
    {
        const float4* q4 = (const float4*)(query + (size_t)b * QD);
        float4 q0 = q4[lane];
        float4 q1 = q4[64 + lane];
        float4 q2 = q4[128 + lane];
        float4 q3 = q4[192 + lane];
        #pragma unroll 2
        for (int i = 0; i < 8; ++i) {
            int a = wid * 8 + i;
            const float4* w4 = (const float4*)(W_w + (size_t)a * QD);
            float4 x0 = w4[lane];
            float4 x1 = w4[64 + lane];
            float4 x2 = w4[128 + lane];
            float4 x3 = w4[192 + lane];
            float accA = 0.f, accB = 0.f;
            accA = fmaf(q0.x, x0.x, fmaf(q0.y, x0.y, fmaf(q0.z, x0.z, fmaf(q0.w, x0.w, accA))));
            accB = fmaf(q1.x, x1.x, fmaf(q1.y, x1.y, fmaf(q1.z, x1.z, fmaf(q1.w, x1.w, accB))));
            accA = fmaf(q2.x, x2.x, fmaf(q2.y, x2.y, fmaf(q2.z, x2.z, fmaf(q2.w, x2.w, accA))));
            accB = fmaf(q3.x, x3.x, fmaf(q3.y, x3.y, fmaf(q3.z, x3.z, fmaf(q3.w, x3.w, accB))));
            float acc = accA + accB;
            #pragma unroll
            for (int off = 32; off; off >>= 1) acc += __shfl_xor(acc, off);
            if (lane == 0) h_lds[a] = tanhf(acc + W_b[a]);
        }
    }
    __syncthreads();   // b1: h_lds + al16 ready

    // ---- P1: g2 (4-way split): G[r] = V_w[r] . h ----
    if (tid < 4 * GN) {
        const int r = tid >> 2;
        const int s = tid & 3;
        const float4* v4 = (const float4*)(V_w + (size_t)r * AD + s * 32);
        const float4* h4 = (const float4*)(h_lds + s * 32);
        float g = 0.f;
        #pragma unroll
        for (int i = 0; i < 8; ++i) {
            float4 vv = v4[i];
            float4 hh = h4[i];
            g = fmaf(vv.x, hh.x, fmaf(vv.y, hh.y, fmaf(vv.z, hh.z, fmaf(vv.w, hh.w, g))));
        }
        g += __shfl_xor(g, 1);
        g += __shfl_xor(g, 2);
        if (s == 0) G_lds[r] = g;
    }

    // ---- P1: prior, wave-local ----
    const int t0w = wid * 128;
    #pragma unroll
    for (int tt = 0; tt < 2; ++tt) {
        int t = t0w + tt * 64 + lane;
        float pr = 0.f;
        #pragma unroll
        for (int k = 0; k < PLn; ++k) pr = fmaf((float)al16[t + k], P[k], pr);
        pcb[t] = fmaxf(pr, 1e-6f);
    }

    // ---- P1: in-lane v-weights: vnq[n][r] = -2*v_w[n*16 + quad*4 + r] ----
    f32x4 vnq[8];
    float vsum = 0.f;
    #pragma unroll
    for (int n = 0; n < 8; ++n) {
        f32x4 vq = *(const f32x4*)(v_w + n * 16 + quad * 4);
        vsum += vq[0] + vq[1] + vq[2] + vq[3];
        vq[0] *= -2.f; vq[1] *= -2.f; vq[2] *= -2.f; vq[3] *= -2.f;
        vnq[n] = vq;
    }
    vsum += __shfl_xor(vsum, 16);
    vsum += __shfl_xor(vsum, 32);   // full sum over 128 a's

    // ---- P1: M-build fragments with no G dependency ----
    // Wave w: atile = w&7 (a-rows atile*16..+15), ktile = w>>3 (k-cols ktile*16..+15)
    const int atile = wid & 7;
    const int ktile = wid >> 3;
    const int kcol  = ktile * 16 + l15;          // 0..31

    // A-frag: A[m=a_loc=l15][c=quad*8+j]: c<8 -> U row, 8..15 -> T row, else 0
    f16x8 Am = {};
    if (quad < 2) {
        const int a = atile * 16 + l15;
        const float* src = (quad == 0) ? (U_w + a * 8) : (T_w + a * 8);
        float4 lo = ((const float4*)src)[0];
        float4 hi = ((const float4*)src)[1];
        Am[0] = (_Float16)lo.x; Am[1] = (_Float16)lo.y;
        Am[2] = (_Float16)lo.z; Am[3] = (_Float16)lo.w;
        Am[4] = (_Float16)hi.x; Am[5] = (_Float16)hi.y;
        Am[6] = (_Float16)hi.z; Am[7] = (_Float16)hi.w;
    }
    // B-frag: B[c=quad*8+j][n=kcol]: quad0 = F[c][kcol] (global, G-independent)
    f16x8 Bm = {};
    if (quad == 0 && kcol < DKn) {
        #pragma unroll
        for (int j = 0; j < 8; ++j) Bm[j] = (_Float16)F_w[j * DKn + kcol];
    }

    __syncthreads();   // b2: G_lds ready

    // ---- P2: finish B-frag (G part) and build M16 ----
    if (quad == 1 && kcol < DKn) {
        #pragma unroll
        for (int j = 0; j < 8; ++j) Bm[j] = (_Float16)G_lds[j * DKn + kcol];
    }
    {
        f32x4 z = {};
        f32x4 Dm = __builtin_amdgcn_mfma_f32_16x16x32_f16(Am, Bm, z, 0, 0, 0);
        // D[m=a_loc=quad*4+r][n=kcol]; cols kcol>=21 are 0 (B cols zeroed).
        #pragma unroll
        for (int r = 0; r < 4; ++r) {
            int a = atile * 16 + quad * 4 + r;
            float val = TWO_LOG2E * Dm[r];
            if (ktile == 1 && l15 == 5) val = TWO_LOG2E * T_b[a];  // k=21 bias col
            M16[a * MS + kcol] = (_Float16)val;
        }
    }
    __syncthreads();   // b3: M16 ready

    // ---- P3: fused weight frags Mf[n]: A[m=a_loc=l15][k=quad*8+j] ----
    f16x8 Mf[8];
    #pragma unroll
    for (int n = 0; n < 8; ++n)
        Mf[n] = *(const f16x8*)&M16[(n * 16 + l15) * MS + quad * 8];

    // ---- main loop: 4 iterations of 2 tiles (32 t), all MFMAs independent ----
    float wsum = 0.f;

    #pragma unroll 1
    for (int m = 0; m < 8; m += 2) {
        const int ta  = t0w + m * 16;
        const int tb_ = ta + 16;

        // al-frags (MFMA *B* operand): B[k=tap=quad*8+j][n=t_loc=l15]
        f16x8 Ac0, Ac1;
        #pragma unroll
        for (int j = 0; j < 8; ++j) {
            Ac0[j] = al16[ta  + l15 + quad * 8 + j];
            Ac1[j] = al16[tb_ + l15 + quad * 8 + j];
        }
        if (quad == 2) {            // k=21 bias channel rides a 1.0 input
            Ac0[5] = (_Float16)1.f;
            Ac1[5] = (_Float16)1.f;
        }

        float es0 = 0.f, es1 = 0.f;
        #pragma unroll
        for (int n = 0; n < 8; ++n) {
            f32x4 z2 = {};
            // d = 2*log2(e) * z ; D[m=a_loc=quad*4+r][n=t=l15]
            f32x4 d0 = __builtin_amdgcn_mfma_f32_16x16x32_f16(Mf[n], Ac0, z2, 0, 0, 0);
            f32x4 d1 = __builtin_amdgcn_mfma_f32_16x16x32_f16(Mf[n], Ac1, z2, 0, 0, 0);
            #pragma unroll
            for (int r = 0; r < 4; ++r) {
                float qa = __builtin_amdgcn_exp2f(d0[r]);
                float qb = __builtin_amdgcn_exp2f(d1[r]);
                float ra = __builtin_amdgcn_rcpf(qa + 1.f);
                float rb = __builtin_amdgcn_rcpf(qb + 1.f);
                es0 = fmaf(vnq[n][r], ra, es0);
                es1 = fmaf(vnq[n][r], rb, es1);
            }
        }
        // a-reduction across quads (t = l15 is the lane col)
        es0 += __shfl_xor(es0, 16);
        es0 += __shfl_xor(es0, 32);
        es1 += __shfl_xor(es1, 16);
        es1 += __shfl_xor(es1, 32);

        // epilogue on 32 lanes: tile A -> lanes 0-15, tile B -> lanes 16-31
        if (lane < 32) {
            int t    = ((lane < 16) ? ta : tb_) + l15;
            float e  = (lane < 16) ? es0 : es1;
            float sv = pcb[t] * __expf(e + vsum);
            sden[t] = sv;
            wsum += sv;
        }
    }

    // ---- P4: block sum + normalize ----
    __syncthreads();
    #pragma unroll
    for (int off = 32; off; off >>= 1) wsum += __shfl_xor(wsum, off);
    if (lane == 0) red[wid] = wsum;
    __syncthreads();
    if (wid == 0) {
        float ss = (lane < 16) ? red[lane] : 0.f;
        #pragma unroll
        for (int off = 8; off; off >>= 1) ss += __shfl_xor(ss, off);
        if (lane == 0) bc = ss;
    }
    __syncthreads();
    const float inv = 1.f / bc;
    out[b * Tn + tid]        = sden[tid] * inv;
    out[b * Tn + tid + 1024] = sden[tid + 1024] * inv;
}

// ---------------------------------------------------------------------------
extern "C" void kernel_launch(void* const* d_in, const int* in_sizes, int n_in,
                              void* d_out, int out_size, void* d_ws, size_t ws_size,
                              hipStream_t stream) {
    const float* query = (const float*)d_in[0];
    const float* align = (const float*)d_in[1];
    const float* P     = (const float*)d_in[2];
    const float* W_w   = (const float*)d_in[3];
    const float* W_b   = (const float*)d_in[4];
    const float* V_w   = (const float*)d_in[5];
    const float* F_w   = (const float*)d_in[6];
    const float* U_w   = (const float*)d_in[7];
    const float* T_w   = (const float*)d_in[8];
    const float* T_b   = (const float*)d_in[9];
    const float* v_w   = (const float*)d_in[10];
    float* out = (float*)d_out;

    dca_kernel<<<Bsz, 1024, 0, stream>>>(query, align, P, W_w, W_b, V_w,
                                         F_w, U_w, T_w, T_b, v_w, out);
}